// Round 4
// baseline (471.809 us; speedup 1.0000x reference)
//
#include <hip/hip_runtime.h>

// LinearSelfAttention: out = rot(q) @ (rot(k)^T @ (w*v)), fp16 MFMA.
// Round 4: barrier-free register-fragment GEMMs. No LDS staging in K-loops —
// each wave loads its MFMA fragments straight global->VGPR (16 rows x 64B
// per load, txn-clean) with a 2-deep register double buffer. The compiler
// then pipelines with partial vmcnt waits (no __syncthreads drain).
//
// ws layout (~133.5 MiB):
//   phi_h  [32768][512] f16   @ 0            (33,554,432 B)  } kvp f16[8] aliases
//   wcat   [1536][512]  f16   @ 33,554,432   ( 1,572,864 B)    phi_h after qkv
//   bcat   [1536]       f32   @ 35,127,296   (     6,144 B)
//   qr     [32768][512] f16   @ 35,133,440   (33,554,432 B)
//   krT    [8][512][4096] f16 @ 68,687,872   (33,554,432 B)
//   vwT    [8][512][4096] f16 @ 102,242,304  (33,554,432 B)
//   kvT    [8][512][512] f16  @ 135,796,736  ( 4,194,304 B)

typedef _Float16 f16x8 __attribute__((ext_vector_type(8)));
typedef _Float16 f16x4 __attribute__((ext_vector_type(4)));
typedef float f32x4 __attribute__((ext_vector_type(4)));

// Barrier-free 128x128-block GEMM K-loop (4 waves 2x2, 64x64 per wave,
// 4x4 16x16x32 subtiles), K=512, fragments direct from global.
// A: [128 rows][lda], B: [128 rows][ldb], both row-major with K contiguous.
__device__ __forceinline__ void reg_gemm512(const _Float16* __restrict__ A, int lda,
                                            const _Float16* __restrict__ B, int ldb,
                                            int wm, int wn, int l16, int quad,
                                            f32x4 acc[4][4]) {
    const _Float16* pa[4];
    const _Float16* pb[4];
    #pragma unroll
    for (int mi = 0; mi < 4; mi++)
        pa[mi] = A + (size_t)(wm + mi * 16 + l16) * lda + quad * 8;
    #pragma unroll
    for (int ni = 0; ni < 4; ni++)
        pb[ni] = B + (size_t)(wn + ni * 16 + l16) * ldb + quad * 8;

    f16x8 a0[4], b0[4], a1[4], b1[4];
    #pragma unroll
    for (int i = 0; i < 4; i++) {
        a0[i] = *(const f16x8*)(pa[i]);
        b0[i] = *(const f16x8*)(pb[i]);
    }
    for (int k = 0; k < 512; k += 64) {
        #pragma unroll
        for (int i = 0; i < 4; i++) {
            a1[i] = *(const f16x8*)(pa[i] + k + 32);
            b1[i] = *(const f16x8*)(pb[i] + k + 32);
        }
        #pragma unroll
        for (int mi = 0; mi < 4; mi++)
            #pragma unroll
            for (int ni = 0; ni < 4; ni++)
                acc[mi][ni] = __builtin_amdgcn_mfma_f32_16x16x32_f16(
                    a0[mi], b0[ni], acc[mi][ni], 0, 0, 0);
        if (k + 64 < 512) {
            #pragma unroll
            for (int i = 0; i < 4; i++) {
                a0[i] = *(const f16x8*)(pa[i] + k + 64);
                b0[i] = *(const f16x8*)(pb[i] + k + 64);
            }
        }
        #pragma unroll
        for (int mi = 0; mi < 4; mi++)
            #pragma unroll
            for (int ni = 0; ni < 4; ni++)
                acc[mi][ni] = __builtin_amdgcn_mfma_f32_16x16x32_f16(
                    a1[mi], b1[ni], acc[mi][ni], 0, 0, 0);
    }
}

// ---------------------------------------------------------------- prep ----
__global__ __launch_bounds__(256) void convert_phi(const float* __restrict__ phi,
                                                   _Float16* __restrict__ phi_h) {
    int i = (blockIdx.x * 256 + threadIdx.x) * 4;
    float4 v = *(const float4*)(phi + i);
    f16x4 o = {(_Float16)v.x, (_Float16)v.y, (_Float16)v.z, (_Float16)v.w};
    *(f16x4*)(phi_h + i) = o;
}

__global__ __launch_bounds__(256) void pack_w(
    const float* __restrict__ Wq, const float* __restrict__ Wk,
    const float* __restrict__ Wv, const float* __restrict__ bq,
    const float* __restrict__ bk, const float* __restrict__ bv,
    _Float16* __restrict__ wcat, float* __restrict__ bcat) {
    int j = blockIdx.x;            // 0..1535 output row
    int reg = j >> 9, jr = j & 511;
    const float* W; const float* bias;
    if (reg == 0)      { W = Wq; bias = bq; }
    else if (reg == 1) { W = Wk; bias = bk; }
    else               { W = Wv; bias = bv; }
    int d = (reg < 2) ? ((jr & 1) ? (jr >> 1) + 256 : (jr >> 1)) : jr;
    for (int i = threadIdx.x; i < 512; i += 256)
        wcat[j * 512 + i] = (_Float16)W[d * 512 + i];
    if (threadIdx.x == 0) bcat[j] = bias[d];
}

// ------------------------------------------------------------ QKV GEMM ----
// C[32768][1536] = phi_h @ wcat^T, tile 128x128, register K-loop.
__global__ __launch_bounds__(256) void qkv_kernel(
    const _Float16* __restrict__ phi_h, const _Float16* __restrict__ wcat,
    const float* __restrict__ bcat, const float* __restrict__ coords,
    const float* __restrict__ weights, const float* __restrict__ Wrot,
    _Float16* __restrict__ qr, _Float16* __restrict__ krT,
    _Float16* __restrict__ vwT) {
    __shared__ __align__(16) _Float16 Ts[128 * 136];

    const int tid = threadIdx.x;
    const int lane = tid & 63, wave = tid >> 6;
    const int quad = lane >> 4, l16 = lane & 15;
    const int wm = (wave >> 1) * 64, wn = (wave & 1) * 64;
    const int m0 = blockIdx.y * 128;      // row tile (over B*N)
    const int c0 = blockIdx.x * 128;      // col tile (over 1536)

    f32x4 acc[4][4] = {};
    reg_gemm512(phi_h + (size_t)m0 * 512, 512, wcat + (size_t)c0 * 512, 512,
                wm, wn, l16, quad, acc);

    const int region = c0 >> 9;   // 0=q, 1=k, 2=v (128 | 512: never straddles)
    const float qscale = 0.04419417382415922f;  // 1/sqrt(512)

    float bias[4], w0[4], w1[4], w2[4];
    #pragma unroll
    for (int ni = 0; ni < 4; ni++) {
        int gc = c0 + wn + ni * 16 + l16;
        bias[ni] = bcat[gc];
        if (region < 2) {
            int jp = (gc & 511) >> 1;
            w0[ni] = Wrot[jp * 3];
            w1[ni] = Wrot[jp * 3 + 1];
            w2[ni] = Wrot[jp * 3 + 2];
        }
    }

    if (region == 0) {
        // q: rotary + scale -> Ts[row][col] -> coalesced qr store
        #pragma unroll
        for (int mi = 0; mi < 4; mi++)
            #pragma unroll
            for (int r = 0; r < 4; r++) {
                int row = wm + mi * 16 + quad * 4 + r;
                int gm = m0 + row;
                float x = coords[gm * 3], y = coords[gm * 3 + 1], z = coords[gm * 3 + 2];
                #pragma unroll
                for (int ni = 0; ni < 4; ni++) {
                    float val = (acc[mi][ni][r] + bias[ni]) * qscale;
                    float part = __shfl_xor(val, 1);
                    float ph = x * w0[ni] + y * w1[ni] + z * w2[ni];
                    float sv, cv; __sincosf(ph, &sv, &cv);
                    float res = (l16 & 1) ? (part * sv + val * cv)
                                          : (val * cv - part * sv);
                    Ts[row * 136 + wn + ni * 16 + l16] = (_Float16)res;
                }
            }
        __syncthreads();
        for (int i = tid; i < 2048; i += 256) {
            int row = i >> 4, cv = (i & 15) * 8;
            *(f16x8*)&qr[(m0 + row) * 512 + c0 + cv] = *(f16x8*)&Ts[row * 136 + cv];
        }
    } else {
        // k: rotary; v: *weights. -> Ts[col][row] -> coalesced [b][col][n]
        #pragma unroll
        for (int mi = 0; mi < 4; mi++)
            #pragma unroll
            for (int r = 0; r < 4; r++) {
                int row = wm + mi * 16 + quad * 4 + r;
                int gm = m0 + row;
                if (region == 1) {
                    float x = coords[gm * 3], y = coords[gm * 3 + 1], z = coords[gm * 3 + 2];
                    #pragma unroll
                    for (int ni = 0; ni < 4; ni++) {
                        float val = acc[mi][ni][r] + bias[ni];
                        float part = __shfl_xor(val, 1);
                        float ph = x * w0[ni] + y * w1[ni] + z * w2[ni];
                        float sv, cv; __sincosf(ph, &sv, &cv);
                        float res = (l16 & 1) ? (part * sv + val * cv)
                                              : (val * cv - part * sv);
                        Ts[(wn + ni * 16 + l16) * 136 + row] = (_Float16)res;
                    }
                } else {
                    float wgt = weights[gm];
                    #pragma unroll
                    for (int ni = 0; ni < 4; ni++) {
                        float val = (acc[mi][ni][r] + bias[ni]) * wgt;
                        Ts[(wn + ni * 16 + l16) * 136 + row] = (_Float16)val;
                    }
                }
            }
        __syncthreads();
        _Float16* dst = (region == 1) ? krT : vwT;
        const int b = m0 >> 12, n0 = m0 & 4095, cb = c0 & 511;
        for (int i = tid; i < 2048; i += 256) {
            int col = i >> 4, rv = (i & 15) * 8;
            *(f16x8*)&dst[((size_t)b * 512 + cb + col) * 4096 + n0 + rv] =
                *(f16x8*)&Ts[col * 136 + rv];
        }
    }
}

// ------------------------------------------------------------- kv GEMM ----
// kvp[s][b][e][d] (f16) = sum_{n in split s} vwT[b][e][n]*krT[b][d][n];
// tile 128x128, split-K x8 (K=512 each), register K-loop.
__global__ __launch_bounds__(256) void kv_kernel(
    const _Float16* __restrict__ vwT, const _Float16* __restrict__ krT,
    _Float16* __restrict__ kvp) {
    const int tid = threadIdx.x, lane = tid & 63, wave = tid >> 6;
    const int quad = lane >> 4, l16 = lane & 15;
    const int wm = (wave >> 1) * 64, wn = (wave & 1) * 64;
    const int d0 = blockIdx.x * 128, e0 = blockIdx.y * 128;
    const int b = blockIdx.z >> 3, split = blockIdx.z & 7;
    const size_t base = (size_t)b * 512 * 4096;
    const int kbeg = split * 512;

    f32x4 acc[4][4] = {};
    reg_gemm512(vwT + base + (size_t)e0 * 4096 + kbeg, 4096,
                krT + base + (size_t)d0 * 4096 + kbeg, 4096,
                wm, wn, l16, quad, acc);

    _Float16* dst = kvp + ((size_t)split * 8 + b) * 262144;
    #pragma unroll
    for (int mi = 0; mi < 4; mi++)
        #pragma unroll
        for (int ni = 0; ni < 4; ni++)
            #pragma unroll
            for (int r = 0; r < 4; r++) {
                int e = e0 + wm + mi * 16 + quad * 4 + r;
                int d = d0 + wn + ni * 16 + l16;
                dst[e * 512 + d] = (_Float16)acc[mi][ni][r];
            }
}

// kvT[b][e][d] f16 = sum_s kvp[s][b][e][d]
__global__ __launch_bounds__(256) void reduce_kv(const _Float16* __restrict__ kvp,
                                                 _Float16* __restrict__ kvT) {
    int i = (blockIdx.x * 256 + threadIdx.x) * 8;
    float s[8] = {};
    #pragma unroll
    for (int sp = 0; sp < 8; sp++) {
        f16x8 v = *(const f16x8*)(kvp + (size_t)sp * 2097152 + i);
        #pragma unroll
        for (int j = 0; j < 8; j++) s[j] += (float)v[j];
    }
    f16x8 o;
    #pragma unroll
    for (int j = 0; j < 8; j++) o[j] = (_Float16)s[j];
    *(f16x8*)(kvT + i) = o;
}

// ------------------------------------------------------------ out GEMM ----
// out[gm][e] = sum_d qr[gm][d] * kvT[b][e][d]; tile 128x128, register K-loop.
__global__ __launch_bounds__(256) void out_kernel(
    const _Float16* __restrict__ qr, const _Float16* __restrict__ kvT,
    float* __restrict__ out) {
    const int tid = threadIdx.x, lane = tid & 63, wave = tid >> 6;
    const int quad = lane >> 4, l16 = lane & 15;
    const int wm = (wave >> 1) * 64, wn = (wave & 1) * 64;
    const int m0 = blockIdx.y * 128, e0 = blockIdx.x * 128;
    const int b = m0 >> 12;

    f32x4 acc[4][4] = {};
    reg_gemm512(qr + (size_t)m0 * 512, 512,
                kvT + (size_t)b * 262144 + (size_t)e0 * 512, 512,
                wm, wn, l16, quad, acc);

    #pragma unroll
    for (int mi = 0; mi < 4; mi++)
        #pragma unroll
        for (int ni = 0; ni < 4; ni++)
            #pragma unroll
            for (int r = 0; r < 4; r++) {
                int gm = m0 + wm + mi * 16 + quad * 4 + r;
                int e = e0 + wn + ni * 16 + l16;
                out[(size_t)gm * 512 + e] = acc[mi][ni][r];
            }
}

// -------------------------------------------------------------- launch ----
extern "C" void kernel_launch(void* const* d_in, const int* in_sizes, int n_in,
                              void* d_out, int out_size, void* d_ws, size_t ws_size,
                              hipStream_t stream) {
    const float* phi     = (const float*)d_in[0];
    const float* coords  = (const float*)d_in[1];
    const float* weights = (const float*)d_in[2];
    const float* Wq      = (const float*)d_in[3];
    const float* bq      = (const float*)d_in[4];
    const float* Wk      = (const float*)d_in[5];
    const float* bk      = (const float*)d_in[6];
    const float* Wv      = (const float*)d_in[7];
    const float* bv      = (const float*)d_in[8];
    const float* Wrot    = (const float*)d_in[9];
    float* out = (float*)d_out;

    char* ws = (char*)d_ws;
    _Float16* phi_h = (_Float16*)(ws);
    _Float16* kvp   = (_Float16*)(ws);            // aliases phi_h (dead by then)
    _Float16* wcat  = (_Float16*)(ws + 33554432);
    float*    bcat  = (float*)   (ws + 35127296);
    _Float16* qr    = (_Float16*)(ws + 35133440);
    _Float16* krT   = (_Float16*)(ws + 68687872);
    _Float16* vwT   = (_Float16*)(ws + 102242304);
    _Float16* kvT   = (_Float16*)(ws + 135796736);  // end: 139,991,040 B

    convert_phi<<<16384, 256, 0, stream>>>(phi, phi_h);
    pack_w<<<1536, 256, 0, stream>>>(Wq, Wk, Wv, bq, bk, bv, wcat, bcat);
    qkv_kernel<<<dim3(12, 256), 256, 0, stream>>>(phi_h, wcat, bcat, coords,
                                                  weights, Wrot, qr, krT, vwT);
    kv_kernel<<<dim3(4, 4, 64), 256, 0, stream>>>(vwT, krT, kvp);
    reduce_kv<<<1024, 256, 0, stream>>>(kvp, kvT);
    out_kernel<<<dim3(4, 256), 256, 0, stream>>>(qr, kvT, out);
}

// Round 5
// 441.303 us; speedup vs baseline: 1.0691x; 1.0691x over previous
//
#include <hip/hip_runtime.h>

// LinearSelfAttention: out = rot(q) @ (rot(k)^T @ (w*v)), fp16 MFMA.
// Round 5: B-resident barrier-free GEMMs for qkv/out (B panel 128x512 f16 =
// 128KB in LDS, loaded once per block; waves stream M with zero barriers,
// A read as wave-contiguous "fragged" 1KB loads). kv: seg-major staging
// (conflict-free LDS reads), split-K x4.
//
// Fragged layout: Af[tile][lane][8] f16, tile=(m>>4)*(K>>5)+(k>>5),
//                 lane=((k>>3)&3)*16+(m&15)  -> frag load = base+lane*16B.
//
// ws layout (~133.5 MiB): phi_f@0 (33.5M, kvp aliases), wcat@33554432,
// bcat@35127296, qr_f@35133440, krT@68687872, vwT@102242304, kvT@135796736.

typedef _Float16 f16x8 __attribute__((ext_vector_type(8)));
typedef float f32x4 __attribute__((ext_vector_type(4)));

__device__ __forceinline__ void gl_lds16(const void* g, void* l) {
    __builtin_amdgcn_global_load_lds(
        (const __attribute__((address_space(1))) void*)g,
        (__attribute__((address_space(3))) void*)l, 16, 0, 0);
}

// ---------------------------------------------------------------- prep ----
__global__ __launch_bounds__(256) void convert_phi(const float* __restrict__ phi,
                                                   _Float16* __restrict__ phi_f) {
    int lane = threadIdx.x & 63, wave = threadIdx.x >> 6;
    int t = blockIdx.x * 4 + wave;          // tile id
    int m = (t >> 4) * 16 + (lane & 15);
    int k = (t & 15) * 32 + (lane >> 4) * 8;
    const float* src = phi + (size_t)m * 512 + k;
    float4 u = *(const float4*)src;
    float4 v = *(const float4*)(src + 4);
    f16x8 o = {(_Float16)u.x,(_Float16)u.y,(_Float16)u.z,(_Float16)u.w,
               (_Float16)v.x,(_Float16)v.y,(_Float16)v.z,(_Float16)v.w};
    *(f16x8*)(phi_f + (size_t)t * 512 + lane * 8) = o;
}

__global__ __launch_bounds__(256) void pack_w(
    const float* __restrict__ Wq, const float* __restrict__ Wk,
    const float* __restrict__ Wv, const float* __restrict__ bq,
    const float* __restrict__ bk, const float* __restrict__ bv,
    _Float16* __restrict__ wcat, float* __restrict__ bcat) {
    int j = blockIdx.x;
    int reg = j >> 9, jr = j & 511;
    const float* W; const float* bias;
    if (reg == 0)      { W = Wq; bias = bq; }
    else if (reg == 1) { W = Wk; bias = bk; }
    else               { W = Wv; bias = bv; }
    int d = (reg < 2) ? ((jr & 1) ? (jr >> 1) + 256 : (jr >> 1)) : jr;
    for (int i = threadIdx.x; i < 512; i += 256)
        wcat[j * 512 + i] = (_Float16)W[d * 512 + i];
    if (threadIdx.x == 0) bcat[j] = bias[d];
}

// ------------------------------------------------------------ QKV GEMM ----
// B-resident: block = 128 cols of wcat (full K=512 in LDS, swizzled),
// streams 512 rows (4 iters x 128; wave = 64-row strip x 64-col half).
// Grid (12, 64). Dynamic LDS = 131072 + 4*4608.
__global__ __launch_bounds__(256) void qkv_kernel(
    const _Float16* __restrict__ phi_f, const _Float16* __restrict__ wcat,
    const float* __restrict__ bcat, const float* __restrict__ coords,
    const float* __restrict__ weights, const float* __restrict__ Wrot,
    _Float16* __restrict__ qr_f, _Float16* __restrict__ krT,
    _Float16* __restrict__ vwT) {
    extern __shared__ __align__(16) char smem[];
    _Float16* Bs = (_Float16*)smem;                         // 131072 B
    const int tid = threadIdx.x, lane = tid & 63, wave = tid >> 6;
    const int quad = lane >> 4, l16 = lane & 15;
    const int strip = wave >> 1, ch = wave & 1;
    const int m0 = blockIdx.y * 512, c0 = blockIdx.x * 128;
    _Float16* Tw = (_Float16*)(smem + 131072 + wave * 4608); // per-wave scratch

    // stage B once: chunk c = (kstep<<3)|(colgroup); lane->(col', qslot)
    {
        int qg = (lane & 3) ^ ((lane >> 3) & 3);
        int colsub = lane >> 2;
        for (int c = wave; c < 128; c += 4) {
            int ks = c >> 3, colbase = (c & 7) * 16;
            gl_lds16(&wcat[(size_t)(c0 + colbase + colsub) * 512 + ks * 32 + qg * 8],
                     smem + c * 1024);
        }
    }
    __syncthreads();   // only barrier in the kernel

    const int region = c0 >> 9;   // 0=q 1=k 2=v
    const float qscale = 0.04419417382415922f;  // 1/sqrt(512)
    const int qs8 = (quad ^ ((l16 >> 1) & 3)) * 8;  // B swizzle slot

    float bias[4], w0[4], w1[4], w2[4];
    #pragma unroll
    for (int ni = 0; ni < 4; ni++) {
        int gc = c0 + ch * 64 + ni * 16 + l16;
        bias[ni] = bcat[gc];
        if (region < 2) {
            int jp = (gc & 511) >> 1;
            w0[ni] = Wrot[jp*3]; w1[ni] = Wrot[jp*3+1]; w2[ni] = Wrot[jp*3+2];
        }
    }
    const int b = m0 >> 12, cb = c0 & 511;
    _Float16* dstT = (region == 1) ? krT : vwT;

    for (int iter = 0; iter < 4; iter++) {
        const int R0 = m0 + iter * 128 + strip * 64;
        const _Float16* abase = phi_f + (size_t)(R0 >> 4) * 16 * 512 + lane * 8;
        f32x4 acc[4][4] = {};
        f16x8 a[2][4], bf[2][4];
        #pragma unroll
        for (int mi = 0; mi < 4; mi++) {
            a[0][mi] = *(const f16x8*)(abase + (mi * 16 + 0) * 512);
            a[1][mi] = *(const f16x8*)(abase + (mi * 16 + 1) * 512);
        }
        #pragma unroll
        for (int ni = 0; ni < 4; ni++)
            bf[0][ni] = *(const f16x8*)&Bs[ch * 2048 + ni * 512 + l16 * 32 + qs8];
        #pragma unroll
        for (int ks = 0; ks < 16; ks++) {
            const int cur = ks & 1, nxt = cur ^ 1;
            if (ks < 15) {
                #pragma unroll
                for (int ni = 0; ni < 4; ni++)
                    bf[nxt][ni] = *(const f16x8*)&Bs[(ks+1) * 4096 + ch * 2048
                                                     + ni * 512 + l16 * 32 + qs8];
            }
            #pragma unroll
            for (int mi = 0; mi < 4; mi++)
                #pragma unroll
                for (int ni = 0; ni < 4; ni++)
                    acc[mi][ni] = __builtin_amdgcn_mfma_f32_16x16x32_f16(
                        a[cur][mi], bf[cur][ni], acc[mi][ni], 0, 0, 0);
            if (ks < 14) {
                #pragma unroll
                for (int mi = 0; mi < 4; mi++)
                    a[cur][mi] = *(const f16x8*)(abase + (mi * 16 + ks + 2) * 512);
            }
        }

        if (region == 0) {
            // q: rotary+scale -> per-wave Ts [64 rows][32+2] -> fragged qr
            #pragma unroll
            for (int p = 0; p < 2; p++) {
                #pragma unroll
                for (int mi = 0; mi < 4; mi++)
                    #pragma unroll
                    for (int r = 0; r < 4; r++) {
                        int row = mi * 16 + quad * 4 + r;
                        int gm = R0 + row;
                        float x = coords[gm*3], y = coords[gm*3+1], z = coords[gm*3+2];
                        #pragma unroll
                        for (int ni = 2*p; ni < 2*p + 2; ni++) {
                            float val = (acc[mi][ni][r] + bias[ni]) * qscale;
                            float part = __shfl_xor(val, 1);
                            float ph = x*w0[ni] + y*w1[ni] + z*w2[ni];
                            float sv, cv; __sincosf(ph, &sv, &cv);
                            float res = (l16 & 1) ? (part*sv + val*cv)
                                                  : (val*cv - part*sv);
                            Tw[row * 34 + (ni - 2*p) * 16 + l16] = (_Float16)res;
                        }
                    }
                int ktp = (c0 + ch * 64 + p * 32) >> 5;
                #pragma unroll
                for (int mi = 0; mi < 4; mi++) {
                    f16x8 v = *(f16x8*)&Tw[(mi * 16 + (lane & 15)) * 34 + (lane >> 4) * 8];
                    *(f16x8*)&qr_f[((size_t)((R0 >> 4) + mi) * 16 + ktp) * 512 + lane * 8] = v;
                }
            }
        } else {
            // k: rotary; v: *weights -> per-wave Ts [32 cols][64+2 rows] -> [col][n]
            #pragma unroll
            for (int p = 0; p < 2; p++) {
                #pragma unroll
                for (int mi = 0; mi < 4; mi++)
                    #pragma unroll
                    for (int r = 0; r < 4; r++) {
                        int row = mi * 16 + quad * 4 + r;
                        int gm = R0 + row;
                        if (region == 1) {
                            float x = coords[gm*3], y = coords[gm*3+1], z = coords[gm*3+2];
                            #pragma unroll
                            for (int ni = 2*p; ni < 2*p + 2; ni++) {
                                float val = acc[mi][ni][r] + bias[ni];
                                float part = __shfl_xor(val, 1);
                                float ph = x*w0[ni] + y*w1[ni] + z*w2[ni];
                                float sv, cv; __sincosf(ph, &sv, &cv);
                                float res = (l16 & 1) ? (part*sv + val*cv)
                                                      : (val*cv - part*sv);
                                Tw[((ni - 2*p) * 16 + l16) * 66 + row] = (_Float16)res;
                            }
                        } else {
                            float wgt = weights[gm];
                            #pragma unroll
                            for (int ni = 2*p; ni < 2*p + 2; ni++)
                                Tw[((ni - 2*p) * 16 + l16) * 66 + row] =
                                    (_Float16)((acc[mi][ni][r] + bias[ni]) * wgt);
                        }
                    }
                int n0 = (m0 & 4095) + iter * 128 + strip * 64;
                #pragma unroll
                for (int i = 0; i < 4; i++) {
                    int colp = i * 8 + (lane >> 3);
                    int rowseg = (lane & 7) * 8;
                    f16x8 v = *(f16x8*)&Tw[colp * 66 + rowseg];
                    *(f16x8*)&dstT[((size_t)b * 512 + cb + ch*64 + p*32 + colp) * 4096
                                   + n0 + rowseg] = v;
                }
            }
        }
    }
}

// ------------------------------------------------------------- kv GEMM ----
// seg-major staging (conflict-free frag reads), dbuf, split-K x4 (K=1024).
__device__ __forceinline__ void stage_sm(const _Float16* gA, size_t lda,
                                         const _Float16* gB, size_t ldb,
                                         _Float16* As, _Float16* Bs,
                                         int wave, int lane) {
    const int row = lane & 15;
    const int seg = (lane >> 4) * 8;
    const int c0 = wave * 2, c1 = c0 + 1;
    gl_lds16(&gA[(size_t)(c0*16 + row) * lda + seg], &As[c0 * 512]);
    gl_lds16(&gA[(size_t)(c1*16 + row) * lda + seg], &As[c1 * 512]);
    gl_lds16(&gB[(size_t)(c0*16 + row) * ldb + seg], &Bs[c0 * 512]);
    gl_lds16(&gB[(size_t)(c1*16 + row) * ldb + seg], &Bs[c1 * 512]);
}

__device__ __forceinline__ void mfma_sm(const _Float16* As, const _Float16* Bs,
                                        int wm16, int wn16, int l16, int quad,
                                        f32x4 acc[4][4]) {
    f16x8 af[4], bf[4];
    #pragma unroll
    for (int mi = 0; mi < 4; mi++)
        af[mi] = *(const f16x8*)&As[(wm16 + mi) * 512 + quad * 128 + l16 * 8];
    #pragma unroll
    for (int ni = 0; ni < 4; ni++)
        bf[ni] = *(const f16x8*)&Bs[(wn16 + ni) * 512 + quad * 128 + l16 * 8];
    #pragma unroll
    for (int mi = 0; mi < 4; mi++)
        #pragma unroll
        for (int ni = 0; ni < 4; ni++)
            acc[mi][ni] = __builtin_amdgcn_mfma_f32_16x16x32_f16(
                af[mi], bf[ni], acc[mi][ni], 0, 0, 0);
}

__global__ __launch_bounds__(256) void kv_kernel(
    const _Float16* __restrict__ vwT, const _Float16* __restrict__ krT,
    _Float16* __restrict__ kvp) {
    __shared__ __align__(16) _Float16 As0[4096], Bs0[4096], As1[4096], Bs1[4096];
    const int tid = threadIdx.x, lane = tid & 63, wave = tid >> 6;
    const int quad = lane >> 4, l16 = lane & 15;
    const int wm16 = (wave >> 1) * 4, wn16 = (wave & 1) * 4;
    const int d0 = blockIdx.x * 128, e0 = blockIdx.y * 128;
    const int b = blockIdx.z >> 2, split = blockIdx.z & 3;
    const size_t base = (size_t)b * 512 * 4096;
    const int kbeg = split * 1024;
    const _Float16* gA = vwT + base + (size_t)e0 * 4096 + kbeg;
    const _Float16* gB = krT + base + (size_t)d0 * 4096 + kbeg;
    f32x4 acc[4][4] = {};

    stage_sm(gA, 4096, gB, 4096, As0, Bs0, wave, lane);
    __syncthreads();
    for (int k0 = 0; k0 < 1024; k0 += 64) {
        stage_sm(gA + k0 + 32, 4096, gB + k0 + 32, 4096, As1, Bs1, wave, lane);
        mfma_sm(As0, Bs0, wm16, wn16, l16, quad, acc);
        __syncthreads();
        if (k0 + 64 < 1024)
            stage_sm(gA + k0 + 64, 4096, gB + k0 + 64, 4096, As0, Bs0, wave, lane);
        mfma_sm(As1, Bs1, wm16, wn16, l16, quad, acc);
        __syncthreads();
    }

    _Float16* dst = kvp + ((size_t)split * 8 + b) * 262144;
    #pragma unroll
    for (int mi = 0; mi < 4; mi++)
        #pragma unroll
        for (int ni = 0; ni < 4; ni++)
            #pragma unroll
            for (int r = 0; r < 4; r++) {
                int e = e0 + wm16 * 16 + mi * 16 + quad * 4 + r;
                int d = d0 + wn16 * 16 + ni * 16 + l16;
                dst[e * 512 + d] = (_Float16)acc[mi][ni][r];
            }
}

// kvT[b][e][d] f16 = sum_s kvp[s][b][e][d]
__global__ __launch_bounds__(256) void reduce_kv(const _Float16* __restrict__ kvp,
                                                 _Float16* __restrict__ kvT) {
    int i = (blockIdx.x * 256 + threadIdx.x) * 8;
    float s[8] = {};
    #pragma unroll
    for (int sp = 0; sp < 4; sp++) {
        f16x8 v = *(const f16x8*)(kvp + (size_t)sp * 2097152 + i);
        #pragma unroll
        for (int j = 0; j < 8; j++) s[j] += (float)v[j];
    }
    f16x8 o;
    #pragma unroll
    for (int j = 0; j < 8; j++) o[j] = (_Float16)s[j];
    *(f16x8*)(kvT + i) = o;
}

// ------------------------------------------------------------ out GEMM ----
// B-resident: B = kvT[b] panel 128 e-cols x 512 d (LDS, swizzled); A = qr_f
// fragged. Grid (4, 64). Dynamic LDS = 131072.
__global__ __launch_bounds__(256) void out_kernel(
    const _Float16* __restrict__ qr_f, const _Float16* __restrict__ kvT,
    float* __restrict__ out) {
    extern __shared__ __align__(16) char smem[];
    _Float16* Bs = (_Float16*)smem;
    const int tid = threadIdx.x, lane = tid & 63, wave = tid >> 6;
    const int quad = lane >> 4, l16 = lane & 15;
    const int strip = wave >> 1, ch = wave & 1;
    const int e0 = blockIdx.x * 128, m0 = blockIdx.y * 512;
    const int b = m0 >> 12;

    {
        int qg = (lane & 3) ^ ((lane >> 3) & 3);
        int colsub = lane >> 2;
        const _Float16* kvb = kvT + (size_t)b * 262144;
        for (int c = wave; c < 128; c += 4) {
            int ks = c >> 3, colbase = (c & 7) * 16;
            gl_lds16(&kvb[(size_t)(e0 + colbase + colsub) * 512 + ks * 32 + qg * 8],
                     smem + c * 1024);
        }
    }
    __syncthreads();

    const int qs8 = (quad ^ ((l16 >> 1) & 3)) * 8;

    for (int iter = 0; iter < 4; iter++) {
        const int R0 = m0 + iter * 128 + strip * 64;
        const _Float16* abase = qr_f + (size_t)(R0 >> 4) * 16 * 512 + lane * 8;
        f32x4 acc[4][4] = {};
        f16x8 a[2][4], bf[2][4];
        #pragma unroll
        for (int mi = 0; mi < 4; mi++) {
            a[0][mi] = *(const f16x8*)(abase + (mi * 16 + 0) * 512);
            a[1][mi] = *(const f16x8*)(abase + (mi * 16 + 1) * 512);
        }
        #pragma unroll
        for (int ni = 0; ni < 4; ni++)
            bf[0][ni] = *(const f16x8*)&Bs[ch * 2048 + ni * 512 + l16 * 32 + qs8];
        #pragma unroll
        for (int ks = 0; ks < 16; ks++) {
            const int cur = ks & 1, nxt = cur ^ 1;
            if (ks < 15) {
                #pragma unroll
                for (int ni = 0; ni < 4; ni++)
                    bf[nxt][ni] = *(const f16x8*)&Bs[(ks+1) * 4096 + ch * 2048
                                                     + ni * 512 + l16 * 32 + qs8];
            }
            #pragma unroll
            for (int mi = 0; mi < 4; mi++)
                #pragma unroll
                for (int ni = 0; ni < 4; ni++)
                    acc[mi][ni] = __builtin_amdgcn_mfma_f32_16x16x32_f16(
                        a[cur][mi], bf[cur][ni], acc[mi][ni], 0, 0, 0);
            if (ks < 14) {
                #pragma unroll
                for (int mi = 0; mi < 4; mi++)
                    a[cur][mi] = *(const f16x8*)(abase + (mi * 16 + ks + 2) * 512);
            }
        }
        #pragma unroll
        for (int mi = 0; mi < 4; mi++)
            #pragma unroll
            for (int ni = 0; ni < 4; ni++)
                #pragma unroll
                for (int r = 0; r < 4; r++) {
                    int gm = R0 + mi * 16 + quad * 4 + r;
                    int e = e0 + ch * 64 + ni * 16 + l16;
                    out[(size_t)gm * 512 + e] = acc[mi][ni][r];
                }
    }
}

// -------------------------------------------------------------- launch ----
extern "C" void kernel_launch(void* const* d_in, const int* in_sizes, int n_in,
                              void* d_out, int out_size, void* d_ws, size_t ws_size,
                              hipStream_t stream) {
    const float* phi     = (const float*)d_in[0];
    const float* coords  = (const float*)d_in[1];
    const float* weights = (const float*)d_in[2];
    const float* Wq      = (const float*)d_in[3];
    const float* bq      = (const float*)d_in[4];
    const float* Wk      = (const float*)d_in[5];
    const float* bk      = (const float*)d_in[6];
    const float* Wv      = (const float*)d_in[7];
    const float* bv      = (const float*)d_in[8];
    const float* Wrot    = (const float*)d_in[9];
    float* out = (float*)d_out;

    char* ws = (char*)d_ws;
    _Float16* phi_f = (_Float16*)(ws);
    _Float16* kvp   = (_Float16*)(ws);            // aliases phi_f (dead by then)
    _Float16* wcat  = (_Float16*)(ws + 33554432);
    float*    bcat  = (float*)   (ws + 35127296);
    _Float16* qr_f  = (_Float16*)(ws + 35133440);
    _Float16* krT   = (_Float16*)(ws + 68687872);
    _Float16* vwT   = (_Float16*)(ws + 102242304);
    _Float16* kvT   = (_Float16*)(ws + 135796736);

    (void)hipFuncSetAttribute((const void*)qkv_kernel,
        hipFuncAttributeMaxDynamicSharedMemorySize, 131072 + 4 * 4608);
    (void)hipFuncSetAttribute((const void*)out_kernel,
        hipFuncAttributeMaxDynamicSharedMemorySize, 131072);

    convert_phi<<<8192, 256, 0, stream>>>(phi, phi_f);
    pack_w<<<1536, 256, 0, stream>>>(Wq, Wk, Wv, bq, bk, bv, wcat, bcat);
    qkv_kernel<<<dim3(12, 64), 256, 131072 + 4 * 4608, stream>>>(
        phi_f, wcat, bcat, coords, weights, Wrot, qr_f, krT, vwT);
    kv_kernel<<<dim3(4, 4, 32), 256, 0, stream>>>(vwT, krT, kvp);
    reduce_kv<<<1024, 256, 0, stream>>>(kvp, kvT);
    out_kernel<<<dim3(4, 64), 256, 131072, stream>>>(qr_f, kvT, out);
}